// Round 11
// baseline (291.862 us; speedup 1.0000x reference)
//
#include <hip/hip_runtime.h>

typedef unsigned short u16;
typedef unsigned int u32;
typedef unsigned char u8;
typedef short bf16x8 __attribute__((ext_vector_type(8)));
typedef float f32x4 __attribute__((ext_vector_type(4)));
typedef float f32x16 __attribute__((ext_vector_type(16)));
typedef int i32x4 __attribute__((ext_vector_type(4)));
typedef int i32x8 __attribute__((ext_vector_type(8)));

#define AS1 __attribute__((address_space(1)))
#define AS3 __attribute__((address_space(3)))

#define B_ 2
#define T_ 2048
#define DIM_ 1024
#define HID_ 4096
#define H_ 16
#define KVH_ 4
#define HD_ 64
#define WIN_ 512

// MX scale bytes: activations stored x8 (descale 2^-3 = 124), weights x64 (2^-6 = 121)
#define SCALE_A 0x7C7C7C7C
#define SCALE_B 0x79797979

__device__ __forceinline__ u16 f2bf(float f) {
    union { float f; u32 u; } v; v.f = f;
    u32 r = v.u + 0x7FFFu + ((v.u >> 16) & 1u);
    return (u16)(r >> 16);
}
__device__ __forceinline__ float bf2f(u32 u) {
    union { u32 u; float f; } v; v.u = u << 16;
    return v.f;
}
__device__ __forceinline__ float4 ld4bf(const u16* p) {
    uint2 u = *(const uint2*)p;
    float4 r;
    r.x = bf2f(u.x & 0xFFFFu); r.y = bf2f(u.x >> 16);
    r.z = bf2f(u.y & 0xFFFFu); r.w = bf2f(u.y >> 16);
    return r;
}
__device__ __forceinline__ void load_lds16(const void* g, void* l) {
    __builtin_amdgcn_global_load_lds((AS1 void*)(g), (AS3 void*)(l), 16, 0, 0);
}
#define WAITBAR(N) asm volatile("s_waitcnt vmcnt(" #N ")\n\ts_barrier" ::: "memory")

// ---------------- mega convert + attn rmsnorm (merged: saves a launch, overlaps) ----------------
// blocks [0, 14848): all weights -> fp8 e4m3 (x64). attn/ffn scale = 0.01 damps all
// quant error on the residual 100x, so fp8 is safe for QKV/WO too.
// blocks [14848, 18944): rmsnorm of x (fp32 in, fp8 x8 out), row = blockIdx - 14848.
__global__ __launch_bounds__(256) void mega_cvt(const float* __restrict__ wq,
                                                const float* __restrict__ wk,
                                                const float* __restrict__ wv,
                                                const float* __restrict__ wo,
                                                const float* __restrict__ w1,
                                                const float* __restrict__ w3,
                                                const float* __restrict__ w2,
                                                u8* __restrict__ wqkv8,
                                                u8* __restrict__ wo8,
                                                u8* __restrict__ w13_8,
                                                u8* __restrict__ w2_8,
                                                const float* __restrict__ x,
                                                const float* __restrict__ anw,
                                                u8* __restrict__ xq8) {
    if (blockIdx.x >= 14848) {
        // ---- rmsnorm path ----
        int row = blockIdx.x - 14848, tid = threadIdx.x;
        const float4 v = ((const float4*)(x + (size_t)row * DIM_))[tid];
        float ss = v.x * v.x + v.y * v.y + v.z * v.z + v.w * v.w;
#pragma unroll
        for (int m = 1; m < 64; m <<= 1) ss += __shfl_xor(ss, m);
        __shared__ float part[4];
        if ((tid & 63) == 0) part[tid >> 6] = ss;
        __syncthreads();
        float tot = part[0] + part[1] + part[2] + part[3];
        float r = rsqrtf(tot * (1.0f / DIM_) + 1e-5f) * 8.0f;   // x8 for fp8 encoding
        const float4 wv = ((const float4*)anw)[tid];
        int pk = __builtin_amdgcn_cvt_pk_fp8_f32(v.x * r * wv.x, v.y * r * wv.y, 0, false);
        pk = __builtin_amdgcn_cvt_pk_fp8_f32(v.z * r * wv.z, v.w * r * wv.w, pk, true);
        ((u32*)xq8)[(size_t)row * 256 + tid] = (u32)pk;
        return;
    }
    int i = blockIdx.x * 256 + threadIdx.x;  // global float4 index, < 3801088 exactly
    const float* s; u32* dbase; size_t didx;
    if (i < 655360) {
        if (i < 262144)      { s = wq + (size_t)i * 4; dbase = (u32*)wqkv8; didx = i; }
        else if (i < 327680) { int f = i - 262144; s = wk + (size_t)f * 4; dbase = (u32*)wqkv8; didx = 262144 + f; }
        else if (i < 393216) { int f = i - 327680; s = wv + (size_t)f * 4; dbase = (u32*)wqkv8; didx = 327680 + f; }
        else                 { int f = i - 393216; s = wo + (size_t)f * 4; dbase = (u32*)wo8; didx = f; }
    } else {
        // w1/w3 interleaved in 32-col tiles:
        //   w1 row c -> packed (c>>5)*64 + (c&31);  w3 row c -> packed (c>>5)*64 + 32 + (c&31)
        if (i < 1703936)      { int f = i - 655360;  int c = f >> 8; int n = (c >> 5) * 64 + (c & 31);
                                s = w1 + (size_t)f * 4; dbase = (u32*)w13_8; didx = (size_t)n * 256 + (f & 255); }
        else if (i < 2752512) { int f = i - 1703936; int c = f >> 8; int n = (c >> 5) * 64 + 32 + (c & 31);
                                s = w3 + (size_t)f * 4; dbase = (u32*)w13_8; didx = (size_t)n * 256 + (f & 255); }
        else                  { int f = i - 2752512; s = w2 + (size_t)f * 4; dbase = (u32*)w2_8; didx = f; }
    }
    float4 v = *(const float4*)s;
    int p = __builtin_amdgcn_cvt_pk_fp8_f32(v.x * 64.f, v.y * 64.f, 0, false);
    p = __builtin_amdgcn_cvt_pk_fp8_f32(v.z * 64.f, v.w * 64.f, p, true);
    dbase[didx] = (u32)p;
}

// ---------------- fuse_attn: h = x + (p0+p1+p2+p3)*ascale; xn8 = fp8(rmsnorm(h)*fnw * 8) ----------------
__global__ __launch_bounds__(256) void fuse_attn_kernel(const float* __restrict__ x,
                                                        const u16* __restrict__ p,
                                                        const float* __restrict__ ascale,
                                                        const float* __restrict__ fnw,
                                                        float* __restrict__ h,
                                                        u8* __restrict__ xn8) {
    int row = blockIdx.x, tid = threadIdx.x;
    const float4 xv = ((const float4*)(x + (size_t)row * DIM_))[tid];
    size_t off = (size_t)row * DIM_ + tid * 4;
    float4 a0 = ld4bf(p + off);
    float4 a1 = ld4bf(p + 4194304 + off);
    float4 a2 = ld4bf(p + 8388608 + off);
    float4 a3 = ld4bf(p + 12582912 + off);
    const float4 sc = ((const float4*)ascale)[tid];
    float4 hv;
    hv.x = xv.x + (a0.x + a1.x + a2.x + a3.x) * sc.x;
    hv.y = xv.y + (a0.y + a1.y + a2.y + a3.y) * sc.y;
    hv.z = xv.z + (a0.z + a1.z + a2.z + a3.z) * sc.z;
    hv.w = xv.w + (a0.w + a1.w + a2.w + a3.w) * sc.w;
    ((float4*)(h + (size_t)row * DIM_))[tid] = hv;
    float ss = hv.x * hv.x + hv.y * hv.y + hv.z * hv.z + hv.w * hv.w;
#pragma unroll
    for (int m = 1; m < 64; m <<= 1) ss += __shfl_xor(ss, m);
    __shared__ float part[4];
    if ((tid & 63) == 0) part[tid >> 6] = ss;
    __syncthreads();
    float tot = part[0] + part[1] + part[2] + part[3];
    float r = rsqrtf(tot * (1.0f / DIM_) + 1e-5f) * 8.0f;  // x8 for fp8 encoding
    const float4 wv = ((const float4*)fnw)[tid];
    int pk = __builtin_amdgcn_cvt_pk_fp8_f32(hv.x * r * wv.x, hv.y * r * wv.y, 0, false);
    pk = __builtin_amdgcn_cvt_pk_fp8_f32(hv.z * r * wv.z, hv.w * r * wv.w, pk, true);
    ((u32*)xn8)[(size_t)row * 256 + tid] = (u32)pk;
}

// ---------------- fuse_ffn: out = h + (p0+p1+p2+p3)*fscale (bf16 partials) ----------------
__global__ __launch_bounds__(256) void fuse_ffn_kernel(const float* __restrict__ h,
                                                       const u16* __restrict__ p,
                                                       const float* __restrict__ fscale,
                                                       float* __restrict__ out) {
    int row = blockIdx.x, tid = threadIdx.x;
    const float4 hv = ((const float4*)(h + (size_t)row * DIM_))[tid];
    size_t off = (size_t)row * DIM_ + tid * 4;
    float4 a0 = ld4bf(p + off);
    float4 a1 = ld4bf(p + 4194304 + off);
    float4 a2 = ld4bf(p + 8388608 + off);
    float4 a3 = ld4bf(p + 12582912 + off);
    const float4 sc = ((const float4*)fscale)[tid];
    float4 o;
    o.x = hv.x + (a0.x + a1.x + a2.x + a3.x) * sc.x;
    o.y = hv.y + (a0.y + a1.y + a2.y + a3.y) * sc.y;
    o.z = hv.z + (a0.z + a1.z + a2.z + a3.z) * sc.z;
    o.w = hv.w + (a0.w + a1.w + a2.w + a3.w) * sc.w;
    ((float4*)(out + (size_t)row * DIM_))[tid] = o;
}

// ---------------- QKV post: sum 2 bf16 partials + per-head RMSNorm(1e-6); V^T written directly ----------------
// vtrans kernel eliminated: V is written straight to Vt[bk][d][t] (per-lane 2B scatter,
// ~1M L2 line-touches total ~= 3us, replacing an 8MB round-trip + a launch gap).
__global__ __launch_bounds__(256) void qkv_post_kernel(const u16* __restrict__ qkv,
                                                       const float* __restrict__ qw,
                                                       const float* __restrict__ kw,
                                                       u16* __restrict__ Qb,
                                                       u16* __restrict__ Kb,
                                                       u16* __restrict__ Vt) {
    int bt = blockIdx.x;
    int b = bt >> 11, t = bt & (T_ - 1);
    int wave = threadIdx.x >> 6, lane = threadIdx.x & 63;
    const u16* row0 = qkv + (size_t)bt * 1536;
    const u16* row1 = row0 + 6291456;
    float qwl = qw[lane], kwl = kw[lane];
#pragma unroll
    for (int i = 0; i < 4; i++) {
        int h = wave * 4 + i;
        float v = bf2f(row0[h * 64 + lane]) + bf2f(row1[h * 64 + lane]);
        float ss = v * v;
#pragma unroll
        for (int m = 1; m < 64; m <<= 1) ss += __shfl_xor(ss, m);
        float r = rsqrtf(ss * (1.0f / 64.0f) + 1e-6f);
        Qb[(((size_t)(b * H_ + h)) * T_ + t) * HD_ + lane] = f2bf(v * r * qwl);
    }
    {
        float v = bf2f(row0[1024 + wave * 64 + lane]) + bf2f(row1[1024 + wave * 64 + lane]);
        float ss = v * v;
#pragma unroll
        for (int m = 1; m < 64; m <<= 1) ss += __shfl_xor(ss, m);
        float r = rsqrtf(ss * (1.0f / 64.0f) + 1e-6f);
        Kb[(((size_t)(b * KVH_ + wave)) * T_ + t) * HD_ + lane] = f2bf(v * r * kwl);
        float vv = bf2f(row0[1280 + wave * 64 + lane]) + bf2f(row1[1280 + wave * 64 + lane]);
        // direct V^T write: Vt[b*KVH+wave][lane][t]
        Vt[((size_t)(b * KVH_ + wave) * HD_ + lane) * T_ + t] = f2bf(vv);
    }
}

// ---------------- Flash attention, sliding window 512, GQA 16/4 ----------------
// GQA-SHARED LDS STAGING (validated round 7). Block = (qt, kvh, b), 512 thr =
// 8 waves = (qhalf, head); K-tile + V^T-tile staged once per 64-k step via
// global_load_lds (double-buffered, counted vmcnt(2)) and shared by 4 heads x 2
// q-halves. XOR-swizzled source chunks + same XOR on ds_read (rule 21).
// Epilogue writes fp8 x8 (att8) to feed the fp8 WO GEMM directly.
// NaN guard: mrun sentinel -1e30f (finite).
__global__ __launch_bounds__(512, 2) void flash_kernel(const u16* __restrict__ Qb,
                                                       const u16* __restrict__ Kb,
                                                       const u16* __restrict__ Vt,
                                                       u8* __restrict__ Ob8) {
    const int b = blockIdx.z, kvh = blockIdx.y, qt = blockIdx.x;
    const int q0 = qt * 64;
    const int tid = threadIdx.x, wave = tid >> 6, lane = tid & 63;
    const int head = wave & 3, qhalf = wave >> 2;
    const int h = kvh * 4 + head;
    const int m = lane & 15, quad = lane >> 4;

    __shared__ __align__(16) u16 Ks[2][4096];   // [64 krow][8 chunk16B] swizzled
    __shared__ __align__(16) u16 Vs[2][4096];   // [64 drow][8 chunk16B] swizzled
    __shared__ __align__(16) u16 Ps[8][16 * 72];

    const u16* Qp = Qb + ((size_t)(b * H_ + h) * T_) * HD_;
    const u16* Kp = Kb + ((size_t)(b * KVH_ + kvh) * T_) * HD_;
    const u16* Vp = Vt + ((size_t)(b * KVH_ + kvh) * HD_) * T_;

    const int qbase = q0 + qhalf * 32;           // this wave's 32 rows
    bf16x8 qa[2][2];
#pragma unroll
    for (int qs = 0; qs < 2; qs++) {
        const u16* qp = Qp + (size_t)(qbase + qs * 16 + m) * 64 + quad * 8;
        qa[qs][0] = *(const bf16x8*)(qp);
        qa[qs][1] = *(const bf16x8*)(qp + 32);
    }

    f32x4 o[2][4] = {};                          // [qsub][dsub] O^T
    float mrun[2] = {-1e30f, -1e30f}, lrun[2] = {0.f, 0.f};

    const int kt0 = (q0 >= WIN_) ? ((q0 - (WIN_ - 1)) >> 6) : 0;
    const int kt1 = qt;

    // staging: thread stages one 16B chunk of K and one of V per tile.
    // LDS slot tid holds global chunk (tid&7)^(row&7) of row tid>>3 (XOR pre-swizzle).
    const int srow = tid >> 3;
    const int schunk = (tid & 7) ^ (srow & 7);
    const u16* Ksrc = Kp + (size_t)srow * 64 + schunk * 8;   // + kt*4096 elems
    const u16* Vsrc = Vp + (size_t)srow * T_ + schunk * 8;   // + kt*64 elems
    const int ldsOff = wave * 512;               // u16; HW adds lane*16B

    // prologue: stage tile kt0 into buffer 0
    load_lds16(Ksrc + (size_t)kt0 * 4096, &Ks[0][ldsOff]);
    load_lds16(Vsrc + kt0 * 64, &Vs[0][ldsOff]);

    for (int kt = kt0; kt <= kt1; ++kt) {
        const int kbase = kt << 6;
        const int cur = (kt - kt0) & 1;
        if (kt < kt1) {
            load_lds16(Ksrc + (size_t)(kt + 1) * 4096, &Ks[cur ^ 1][ldsOff]);
            load_lds16(Vsrc + (kt + 1) * 64, &Vs[cur ^ 1][ldsOff]);
            WAITBAR(2);    // tile kt staged; kt+1's 2 loads stay in flight
        } else {
            WAITBAR(0);
        }
        // hoisted fragment reads (swizzled): row r, chunk c -> u16 addr r*64 + (c^(r&7))*8
        bf16x8 kf[4][2], vb[4][2];
#pragma unroll
        for (int st = 0; st < 4; st++) {
            const int r64 = (st * 16 + m) * 64;
#pragma unroll
            for (int hf = 0; hf < 2; hf++) {
                const int c = (((hf << 2) + quad) ^ (m & 7)) * 8;
                kf[st][hf] = *(const bf16x8*)&Ks[cur][r64 + c];
                vb[st][hf] = *(const bf16x8*)&Vs[cur][r64 + c];
            }
        }
#pragma unroll
        for (int qs = 0; qs < 2; qs++) {
            const int qlo_s = qbase + qs * 16;
            if (kbase <= qlo_s + 15 && kbase >= qlo_s - 574) {   // any valid (q,k)
                f32x4 s4[4];
#pragma unroll
                for (int st = 0; st < 4; st++) {
                    f32x4 z = {0.f, 0.f, 0.f, 0.f};
                    z = __builtin_amdgcn_mfma_f32_16x16x32_bf16(kf[st][0], qa[qs][0], z, 0, 0, 0);
                    z = __builtin_amdgcn_mfma_f32_16x16x32_bf16(kf[st][1], qa[qs][1], z, 0, 0, 0);
                    s4[st] = z;
                }
                float v[16];
                const bool full = (kbase + 63 <= qlo_s) && (kbase >= qlo_s - 496);
                if (full) {
#pragma unroll
                    for (int i = 0; i < 16; i++) v[i] = s4[i >> 2][i & 3] * 0.125f;
                } else {
                    const int D = qlo_s + m - kbase - quad * 4;
#pragma unroll
                    for (int st = 0; st < 4; st++)
#pragma unroll
                        for (int r = 0; r < 4; r++) {
                            int diff = D - st * 16 - r;          // q - k
                            v[st * 4 + r] = ((u32)diff < (u32)WIN_) ? s4[st][r] * 0.125f : -INFINITY;
                        }
                }
                float t0 = fmaxf(fmaxf(fmaxf(v[0], v[1]), fmaxf(v[2], v[3])),
                                 fmaxf(fmaxf(v[4], v[5]), fmaxf(v[6], v[7])));
                float t1 = fmaxf(fmaxf(fmaxf(v[8], v[9]), fmaxf(v[10], v[11])),
                                 fmaxf(fmaxf(v[12], v[13]), fmaxf(v[14], v[15])));
                float rmax = fmaxf(t0, t1);
                rmax = fmaxf(rmax, __shfl_xor(rmax, 16));
                rmax = fmaxf(rmax, __shfl_xor(rmax, 32));
                float mnew = fmaxf(mrun[qs], rmax);
                float alpha = __expf(mrun[qs] - mnew);
                float p[16];
#pragma unroll
                for (int i = 0; i < 16; i++) p[i] = __expf(v[i] - mnew);
                float u0 = ((p[0] + p[1]) + (p[2] + p[3])) + ((p[4] + p[5]) + (p[6] + p[7]));
                float u1 = ((p[8] + p[9]) + (p[10] + p[11])) + ((p[12] + p[13]) + (p[14] + p[15]));
                float psum = u0 + u1;
                psum += __shfl_xor(psum, 16);
                psum += __shfl_xor(psum, 32);
                lrun[qs] = lrun[qs] * alpha + psum;
                mrun[qs] = mnew;
#pragma unroll
                for (int d = 0; d < 4; d++) {
                    o[qs][d][0] *= alpha; o[qs][d][1] *= alpha;
                    o[qs][d][2] *= alpha; o[qs][d][3] *= alpha;
                }
#pragma unroll
                for (int st = 0; st < 4; st++) {
                    u32 lo = (u32)f2bf(p[st * 4 + 0]) | ((u32)f2bf(p[st * 4 + 1]) << 16);
                    u32 hi = (u32)f2bf(p[st * 4 + 2]) | ((u32)f2bf(p[st * 4 + 3]) << 16);
                    *(uint2*)&Ps[wave][m * 72 + st * 16 + quad * 4] = make_uint2(lo, hi);
                }
                bf16x8 pa0 = *(const bf16x8*)&Ps[wave][m * 72 + quad * 8];
                bf16x8 pa1 = *(const bf16x8*)&Ps[wave][m * 72 + 32 + quad * 8];
#pragma unroll
                for (int d = 0; d < 4; d++) {
                    o[qs][d] = __builtin_amdgcn_mfma_f32_16x16x32_bf16(vb[d][0], pa0, o[qs][d], 0, 0, 0);
                    o[qs][d] = __builtin_amdgcn_mfma_f32_16x16x32_bf16(vb[d][1], pa1, o[qs][d], 0, 0, 0);
                }
            }
        }
        asm volatile("s_barrier" ::: "memory");  // all waves done reading buf cur
    }
    // epilogue: per qsub, O^T -> att8[qrow][h*64 + d], fp8 x8
#pragma unroll
    for (int qs = 0; qs < 2; qs++) {
        float inv = 8.0f / lrun[qs];             // x8 for fp8 encoding
        u8* ob = Ob8 + ((size_t)(b * T_ + qbase + qs * 16 + m)) * (H_ * HD_) + h * HD_;
#pragma unroll
        for (int d = 0; d < 4; d++) {
            int pk = __builtin_amdgcn_cvt_pk_fp8_f32(o[qs][d][0] * inv, o[qs][d][1] * inv, 0, false);
            pk = __builtin_amdgcn_cvt_pk_fp8_f32(o[qs][d][2] * inv, o[qs][d][3] * inv, pk, true);
            *(u32*)(ob + d * 16 + quad * 4) = (u32)pk;
        }
    }
}

// ---------------- fp8 MX GEMM (32x32x64 f8f6f4), 256x256 tile, COALESCED staging ----------------
// FROZEN at r9 state. 8 consecutive lanes read the 8 chunks of the SAME row
// (coalesced, 16 req/instr). LDS row-major [256 rows][128B], both-sides XOR swizzle
// (rule 21). Schedule: bar -> STAGE(t+1) -> vmcnt(8)+bar -> ds_read+MFMA (counted).
// MODE 0: bf16 partials at z*M*N. MODE 1: fused SwiGLU (32-col interleave) -> fp8(x8).
#define MFMA8(a, b, c) __builtin_amdgcn_mfma_scale_f32_32x32x64_f8f6f4(a, b, c, 0, 0, 0, SCALE_A, 0, SCALE_B)
#define PHASE_MFMA(I0, I1)                           \
    __builtin_amdgcn_s_setprio(1);                   \
    acc[I0][0] = MFMA8(a0, bf0, acc[I0][0]);         \
    acc[I0][1] = MFMA8(a0, bf1, acc[I0][1]);         \
    acc[I1][0] = MFMA8(a1, bf0, acc[I1][0]);         \
    acc[I1][1] = MFMA8(a1, bf1, acc[I1][1]);         \
    __builtin_amdgcn_s_setprio(0);

template <int MODE>
__global__ __launch_bounds__(512) void gemm_fp8(const u8* __restrict__ A,
                                                const u8* __restrict__ Bt,
                                                u16* __restrict__ Cb,
                                                u8* __restrict__ C8,
                                                int M, int N, int K, int KS) {
    __shared__ __align__(16) u8 As[2][32768];
    __shared__ __align__(16) u8 Bs[2][32768];
    const int tid = threadIdx.x, wave = tid >> 6, lane = tid & 63;
    const int l31 = lane & 31, lh = lane >> 5;
    const int m0 = blockIdx.y * 256, n0 = blockIdx.x * 256;
    const int wm = (wave >> 2) * 128, wn = (wave & 3) * 64;
    const int kb = blockIdx.z * KS;
    const int KT = KS >> 7;

    const u8* Ab = A + (size_t)m0 * K;
    const u8* Bb = Bt + (size_t)n0 * K;

    auto STAGE = [&](const u8* src, int kk, int h, u8* lds) {
#pragma unroll
        for (int p = 0; p < 2; p++) {
            const int s = p * 512 + tid;
            const int r = (h << 7) + (s >> 3);
            const int c = (s & 7) ^ (r & 7);
            load_lds16(src + (size_t)r * K + kk + c * 16,
                       lds + (h << 14) + (p << 13) + (wave << 10));
        }
    };
    auto FRAG = [&](const u8* t, int ks, int row) -> i32x8 {
        const int c0 = ks * 4 + (lh << 1);
        const u8* rp = t + row * 128;
        union { i32x4 h[2]; i32x8 v; } u;
        u.h[0] = *(const i32x4*)(rp + ((c0 ^ (row & 7)) << 4));
        u.h[1] = *(const i32x4*)(rp + (((c0 + 1) ^ (row & 7)) << 4));
        return u.v;
    };

    f32x16 acc[4][2] = {};

    // prologue: stage tile 0 into buffer 0 (8 loads/thread)
    STAGE(Ab, kb, 0, As[0]);
    STAGE(Ab, kb, 1, As[0]);
    STAGE(Bb, kb, 0, Bs[0]);
    STAGE(Bb, kb, 1, Bs[0]);

    for (int kt = 0; kt < KT; ++kt) {
        const int cur = kt & 1;
        if (kt + 1 < KT) {
            asm volatile("s_barrier" ::: "memory");
            const int kn = kb + (kt + 1) * 128;
            STAGE(Ab, kn, 0, As[1 - cur]);
            STAGE(Ab, kn, 1, As[1 - cur]);
            STAGE(Bb, kn, 0, Bs[1 - cur]);
            STAGE(Bb, kn, 1, Bs[1 - cur]);
            WAITBAR(8);   // tile kt's 8 loads done; kt+1's 8 stay in flight
        } else {
            WAITBAR(0);
        }
        const u8* Ac = As[cur];
        const u8* Bc = Bs[cur];
        i32x8 bf0, bf1, a0, a1;
#pragma unroll
        for (int ks = 0; ks < 2; ks++) {
            bf0 = FRAG(Bc, ks, wn + l31);
            bf1 = FRAG(Bc, ks, wn + 32 + l31);
            a0 = FRAG(Ac, ks, wm + l31);
            a1 = FRAG(Ac, ks, wm + 32 + l31);
            PHASE_MFMA(0, 1)
            a0 = FRAG(Ac, ks, wm + 64 + l31);
            a1 = FRAG(Ac, ks, wm + 96 + l31);
            PHASE_MFMA(2, 3)
        }
    }

    if (MODE == 0) {
        u16* Cz = Cb + (size_t)blockIdx.z * M * N;
#pragma unroll
        for (int i = 0; i < 4; i++)
#pragma unroll
            for (int j = 0; j < 2; j++) {
                int col = n0 + wn + j * 32 + l31;
#pragma unroll
                for (int reg = 0; reg < 16; reg++) {
                    int row = m0 + wm + i * 32 + (reg & 3) + 8 * (reg >> 2) + 4 * lh;
                    Cz[(size_t)row * N + col] = f2bf(acc[i][j][reg]);
                }
            }
    } else {
        // SwiGLU: acc[i][0] = g1-tile, acc[i][1] = g3-tile for same 32 real cols
        int c = (n0 >> 1) + (wn >> 1) + l31;
#pragma unroll
        for (int i = 0; i < 4; i++)
#pragma unroll
            for (int reg = 0; reg < 16; reg++) {
                int row = m0 + wm + i * 32 + (reg & 3) + 8 * (reg >> 2) + 4 * lh;
                float g1 = acc[i][0][reg], g3 = acc[i][1][reg];
                float res = (g1 / (1.f + __expf(-g1))) * g3 * 8.0f;  // x8 for fp8 encoding
                int p = __builtin_amdgcn_cvt_pk_fp8_f32(res, res, 0, false);
                C8[(size_t)row * (N >> 1) + c] = (u8)(p & 0xFF);
            }
    }
}

extern "C" void kernel_launch(void* const* d_in, const int* in_sizes, int n_in,
                              void* d_out, int out_size, void* d_ws, size_t ws_size,
                              hipStream_t stream) {
    const float* x = (const float*)d_in[0];
    const float* wq = (const float*)d_in[1];
    const float* wk = (const float*)d_in[2];
    const float* wv = (const float*)d_in[3];
    const float* wo = (const float*)d_in[4];
    const float* w1 = (const float*)d_in[5];
    const float* w2 = (const float*)d_in[6];
    const float* w3 = (const float*)d_in[7];
    const float* qnw = (const float*)d_in[8];
    const float* knw = (const float*)d_in[9];
    const float* anw = (const float*)d_in[10];
    const float* fnw = (const float*)d_in[11];
    const float* ascale = (const float*)d_in[12];
    const float* fscale = (const float*)d_in[13];
    float* out = (float*)d_out;

    // ---- workspace layout (~114 MiB) ----
    char* ws = (char*)d_ws;
    u8* wqkv8 = (u8*)(ws + 0);              // [1536][1024] fp8 (x64)
    u8* wo8 = (u8*)(ws + 1572864);          // [1024][1024] fp8 (x64)
    u8* w13_8 = (u8*)(ws + 5242880);        // [8192][1024] fp8 (x64, 32-col interleave)
    u8* w2_8 = (u8*)(ws + 13631488);        // [1024][4096] fp8 (x64)
    u8* xq8 = (u8*)(ws + 17825792);         // [4096][1024] fp8 (x8, attn-norm out)
    u8* xn8 = (u8*)(ws + 26214400);         // [4096][1024] fp8 (x8, ffn-norm out)
    float* h_f = (float*)(ws + 30408704);   // [4096][1024] fp32
    char* P = ws + 47185920;                // overlay pool (67.1 MB)
    u16* qkv_part = (u16*)(P + 0);          // 2x[4096][1536] bf16 partials
    u16* Qb = (u16*)(P + 25165824);
    u16* Kb = (u16*)(P + 33554432);
    u8* att8 = (u8*)(P + 37748736);         // [4096][1024] fp8 (x8, flash out)
    u16* Vt = (u16*)(P + 46137344);         // [8][64][2048] bf16 (V^T, written by qkv_post)
    u16* wo_part = (u16*)(P + 0);           // 4x[4096][1024] bf16 (after flash; reuses qkv_part+Qb/Kb)
    u8* gsw8 = (u8*)(P + 16777216);         // [4096][4096] fp8
    u16* w2_part = (u16*)(P + 33554432);    // 4x[4096][1024] bf16 (after att8/Vt dead)

    // weights -> fp8 + attn rmsnorm, one launch
    mega_cvt<<<18944, 256, 0, stream>>>(wq, wk, wv, wo, w1, w3, w2,
                                        wqkv8, wo8, w13_8, w2_8, x, anw, xq8);
    // QKV projection: fp8 MX GEMM, split-K=2 -> bf16 partials (192 blocks)
    gemm_fp8<0><<<dim3(6, 16, 2), 512, 0, stream>>>(xq8, wqkv8, qkv_part, nullptr,
                                                    4096, 1536, 1024, 512);
    // partial sum + per-head norms; writes Q, K and V^T directly (vtrans eliminated)
    qkv_post_kernel<<<4096, 256, 0, stream>>>(qkv_part, qnw, knw, Qb, Kb, Vt);
    // GQA-shared flash: grid (qt, kvh, b) = 256 blocks, 8 waves = 4 heads x 2 q-halves
    flash_kernel<<<dim3(32, KVH_, B_), 512, 0, stream>>>(Qb, Kb, Vt, att8);
    // out-proj: fp8 MX GEMM, split-K=4 -> bf16 partials (256 blocks = 1 CU round)
    gemm_fp8<0><<<dim3(4, 16, 4), 512, 0, stream>>>(att8, wo8, wo_part, nullptr,
                                                    4096, 1024, 1024, 256);
    fuse_attn_kernel<<<4096, 256, 0, stream>>>(x, wo_part, ascale, fnw, h_f, xn8);
    // w1|w3 fp8-MX GEMM with fused SwiGLU -> gsw8 (512 blocks)
    gemm_fp8<1><<<dim3(32, 16, 1), 512, 0, stream>>>(xn8, w13_8, nullptr, gsw8,
                                                     4096, 8192, 1024, 1024);
    // w2 fp8-MX GEMM, split-K=4 -> bf16 partials (256 blocks = 1 CU round)
    gemm_fp8<0><<<dim3(4, 16, 4), 512, 0, stream>>>(gsw8, w2_8, w2_part, nullptr,
                                                    4096, 1024, 4096, 1024);
    fuse_ffn_kernel<<<4096, 256, 0, stream>>>(h_f, w2_part, fscale, out);
}

// Round 12
// 289.578 us; speedup vs baseline: 1.0079x; 1.0079x over previous
//
#include <hip/hip_runtime.h>

typedef unsigned short u16;
typedef unsigned int u32;
typedef unsigned char u8;
typedef short bf16x8 __attribute__((ext_vector_type(8)));
typedef float f32x4 __attribute__((ext_vector_type(4)));
typedef float f32x16 __attribute__((ext_vector_type(16)));
typedef int i32x4 __attribute__((ext_vector_type(4)));
typedef int i32x8 __attribute__((ext_vector_type(8)));

#define AS1 __attribute__((address_space(1)))
#define AS3 __attribute__((address_space(3)))

#define B_ 2
#define T_ 2048
#define DIM_ 1024
#define HID_ 4096
#define H_ 16
#define KVH_ 4
#define HD_ 64
#define WIN_ 512

// MX scale bytes: activations stored x8 (descale 2^-3 = 124), weights x64 (2^-6 = 121)
#define SCALE_A 0x7C7C7C7C
#define SCALE_B 0x79797979

__device__ __forceinline__ u16 f2bf(float f) {
    union { float f; u32 u; } v; v.f = f;
    u32 r = v.u + 0x7FFFu + ((v.u >> 16) & 1u);
    return (u16)(r >> 16);
}
__device__ __forceinline__ float bf2f(u32 u) {
    union { u32 u; float f; } v; v.u = u << 16;
    return v.f;
}
__device__ __forceinline__ float4 ld4bf(const u16* p) {
    uint2 u = *(const uint2*)p;
    float4 r;
    r.x = bf2f(u.x & 0xFFFFu); r.y = bf2f(u.x >> 16);
    r.z = bf2f(u.y & 0xFFFFu); r.w = bf2f(u.y >> 16);
    return r;
}
__device__ __forceinline__ void load_lds16(const void* g, void* l) {
    __builtin_amdgcn_global_load_lds((AS1 void*)(g), (AS3 void*)(l), 16, 0, 0);
}
#define WAITBAR(N) asm volatile("s_waitcnt vmcnt(" #N ")\n\ts_barrier" ::: "memory")

// ---------------- mega convert + attn rmsnorm (merged) ----------------
__global__ __launch_bounds__(256) void mega_cvt(const float* __restrict__ wq,
                                                const float* __restrict__ wk,
                                                const float* __restrict__ wv,
                                                const float* __restrict__ wo,
                                                const float* __restrict__ w1,
                                                const float* __restrict__ w3,
                                                const float* __restrict__ w2,
                                                u8* __restrict__ wqkv8,
                                                u8* __restrict__ wo8,
                                                u8* __restrict__ w13_8,
                                                u8* __restrict__ w2_8,
                                                const float* __restrict__ x,
                                                const float* __restrict__ anw,
                                                u8* __restrict__ xq8) {
    if (blockIdx.x >= 14848) {
        // ---- rmsnorm path ----
        int row = blockIdx.x - 14848, tid = threadIdx.x;
        const float4 v = ((const float4*)(x + (size_t)row * DIM_))[tid];
        float ss = v.x * v.x + v.y * v.y + v.z * v.z + v.w * v.w;
#pragma unroll
        for (int m = 1; m < 64; m <<= 1) ss += __shfl_xor(ss, m);
        __shared__ float part[4];
        if ((tid & 63) == 0) part[tid >> 6] = ss;
        __syncthreads();
        float tot = part[0] + part[1] + part[2] + part[3];
        float r = rsqrtf(tot * (1.0f / DIM_) + 1e-5f) * 8.0f;   // x8 for fp8 encoding
        const float4 wv = ((const float4*)anw)[tid];
        int pk = __builtin_amdgcn_cvt_pk_fp8_f32(v.x * r * wv.x, v.y * r * wv.y, 0, false);
        pk = __builtin_amdgcn_cvt_pk_fp8_f32(v.z * r * wv.z, v.w * r * wv.w, pk, true);
        ((u32*)xq8)[(size_t)row * 256 + tid] = (u32)pk;
        return;
    }
    int i = blockIdx.x * 256 + threadIdx.x;  // global float4 index, < 3801088 exactly
    const float* s; u32* dbase; size_t didx;
    if (i < 655360) {
        if (i < 262144)      { s = wq + (size_t)i * 4; dbase = (u32*)wqkv8; didx = i; }
        else if (i < 327680) { int f = i - 262144; s = wk + (size_t)f * 4; dbase = (u32*)wqkv8; didx = 262144 + f; }
        else if (i < 393216) { int f = i - 327680; s = wv + (size_t)f * 4; dbase = (u32*)wqkv8; didx = 327680 + f; }
        else                 { int f = i - 393216; s = wo + (size_t)f * 4; dbase = (u32*)wo8; didx = f; }
    } else {
        // w1/w3 interleaved in 32-col tiles:
        //   w1 row c -> packed (c>>5)*64 + (c&31);  w3 row c -> packed (c>>5)*64 + 32 + (c&31)
        if (i < 1703936)      { int f = i - 655360;  int c = f >> 8; int n = (c >> 5) * 64 + (c & 31);
                                s = w1 + (size_t)f * 4; dbase = (u32*)w13_8; didx = (size_t)n * 256 + (f & 255); }
        else if (i < 2752512) { int f = i - 1703936; int c = f >> 8; int n = (c >> 5) * 64 + 32 + (c & 31);
                                s = w3 + (size_t)f * 4; dbase = (u32*)w13_8; didx = (size_t)n * 256 + (f & 255); }
        else                  { int f = i - 2752512; s = w2 + (size_t)f * 4; dbase = (u32*)w2_8; didx = f; }
    }
    float4 v = *(const float4*)s;
    int p = __builtin_amdgcn_cvt_pk_fp8_f32(v.x * 64.f, v.y * 64.f, 0, false);
    p = __builtin_amdgcn_cvt_pk_fp8_f32(v.z * 64.f, v.w * 64.f, p, true);
    dbase[didx] = (u32)p;
}

// ---------------- fuse_attn: h = x + p0*ascale; xn8 = fp8(rmsnorm(h)*fnw * 8) ----------------
// single partial now (WO GEMM runs z=1)
__global__ __launch_bounds__(256) void fuse_attn_kernel(const float* __restrict__ x,
                                                        const u16* __restrict__ p,
                                                        const float* __restrict__ ascale,
                                                        const float* __restrict__ fnw,
                                                        float* __restrict__ h,
                                                        u8* __restrict__ xn8) {
    int row = blockIdx.x, tid = threadIdx.x;
    const float4 xv = ((const float4*)(x + (size_t)row * DIM_))[tid];
    float4 a0 = ld4bf(p + (size_t)row * DIM_ + tid * 4);
    const float4 sc = ((const float4*)ascale)[tid];
    float4 hv;
    hv.x = xv.x + a0.x * sc.x;
    hv.y = xv.y + a0.y * sc.y;
    hv.z = xv.z + a0.z * sc.z;
    hv.w = xv.w + a0.w * sc.w;
    ((float4*)(h + (size_t)row * DIM_))[tid] = hv;
    float ss = hv.x * hv.x + hv.y * hv.y + hv.z * hv.z + hv.w * hv.w;
#pragma unroll
    for (int m = 1; m < 64; m <<= 1) ss += __shfl_xor(ss, m);
    __shared__ float part[4];
    if ((tid & 63) == 0) part[tid >> 6] = ss;
    __syncthreads();
    float tot = part[0] + part[1] + part[2] + part[3];
    float r = rsqrtf(tot * (1.0f / DIM_) + 1e-5f) * 8.0f;  // x8 for fp8 encoding
    const float4 wv = ((const float4*)fnw)[tid];
    int pk = __builtin_amdgcn_cvt_pk_fp8_f32(hv.x * r * wv.x, hv.y * r * wv.y, 0, false);
    pk = __builtin_amdgcn_cvt_pk_fp8_f32(hv.z * r * wv.z, hv.w * r * wv.w, pk, true);
    ((u32*)xn8)[(size_t)row * 256 + tid] = (u32)pk;
}

// ---------------- fuse_ffn: out = h + p0*fscale (single bf16 partial, w2 z=1) ----------------
__global__ __launch_bounds__(256) void fuse_ffn_kernel(const float* __restrict__ h,
                                                       const u16* __restrict__ p,
                                                       const float* __restrict__ fscale,
                                                       float* __restrict__ out) {
    int row = blockIdx.x, tid = threadIdx.x;
    const float4 hv = ((const float4*)(h + (size_t)row * DIM_))[tid];
    float4 a0 = ld4bf(p + (size_t)row * DIM_ + tid * 4);
    const float4 sc = ((const float4*)fscale)[tid];
    float4 o;
    o.x = hv.x + a0.x * sc.x;
    o.y = hv.y + a0.y * sc.y;
    o.z = hv.z + a0.z * sc.z;
    o.w = hv.w + a0.w * sc.w;
    ((float4*)(out + (size_t)row * DIM_))[tid] = o;
}

// ---------------- QKV post: per-head RMSNorm(1e-6) on single partial; V^T written directly ----------------
__global__ __launch_bounds__(256) void qkv_post_kernel(const u16* __restrict__ qkv,
                                                       const float* __restrict__ qw,
                                                       const float* __restrict__ kw,
                                                       u16* __restrict__ Qb,
                                                       u16* __restrict__ Kb,
                                                       u16* __restrict__ Vt) {
    int bt = blockIdx.x;
    int b = bt >> 11, t = bt & (T_ - 1);
    int wave = threadIdx.x >> 6, lane = threadIdx.x & 63;
    const u16* row0 = qkv + (size_t)bt * 1536;
    float qwl = qw[lane], kwl = kw[lane];
#pragma unroll
    for (int i = 0; i < 4; i++) {
        int h = wave * 4 + i;
        float v = bf2f(row0[h * 64 + lane]);
        float ss = v * v;
#pragma unroll
        for (int m = 1; m < 64; m <<= 1) ss += __shfl_xor(ss, m);
        float r = rsqrtf(ss * (1.0f / 64.0f) + 1e-6f);
        Qb[(((size_t)(b * H_ + h)) * T_ + t) * HD_ + lane] = f2bf(v * r * qwl);
    }
    {
        float v = bf2f(row0[1024 + wave * 64 + lane]);
        float ss = v * v;
#pragma unroll
        for (int m = 1; m < 64; m <<= 1) ss += __shfl_xor(ss, m);
        float r = rsqrtf(ss * (1.0f / 64.0f) + 1e-6f);
        Kb[(((size_t)(b * KVH_ + wave)) * T_ + t) * HD_ + lane] = f2bf(v * r * kwl);
        float vv = bf2f(row0[1280 + wave * 64 + lane]);
        Vt[((size_t)(b * KVH_ + wave) * HD_ + lane) * T_ + t] = f2bf(vv);
    }
}

// ---------------- Flash attention, sliding window 512, GQA 16/4 ----------------
// GQA-SHARED LDS STAGING (validated round 7). Unchanged from r10.
__global__ __launch_bounds__(512, 2) void flash_kernel(const u16* __restrict__ Qb,
                                                       const u16* __restrict__ Kb,
                                                       const u16* __restrict__ Vt,
                                                       u8* __restrict__ Ob8) {
    const int b = blockIdx.z, kvh = blockIdx.y, qt = blockIdx.x;
    const int q0 = qt * 64;
    const int tid = threadIdx.x, wave = tid >> 6, lane = tid & 63;
    const int head = wave & 3, qhalf = wave >> 2;
    const int h = kvh * 4 + head;
    const int m = lane & 15, quad = lane >> 4;

    __shared__ __align__(16) u16 Ks[2][4096];   // [64 krow][8 chunk16B] swizzled
    __shared__ __align__(16) u16 Vs[2][4096];   // [64 drow][8 chunk16B] swizzled
    __shared__ __align__(16) u16 Ps[8][16 * 72];

    const u16* Qp = Qb + ((size_t)(b * H_ + h) * T_) * HD_;
    const u16* Kp = Kb + ((size_t)(b * KVH_ + kvh) * T_) * HD_;
    const u16* Vp = Vt + ((size_t)(b * KVH_ + kvh) * HD_) * T_;

    const int qbase = q0 + qhalf * 32;           // this wave's 32 rows
    bf16x8 qa[2][2];
#pragma unroll
    for (int qs = 0; qs < 2; qs++) {
        const u16* qp = Qp + (size_t)(qbase + qs * 16 + m) * 64 + quad * 8;
        qa[qs][0] = *(const bf16x8*)(qp);
        qa[qs][1] = *(const bf16x8*)(qp + 32);
    }

    f32x4 o[2][4] = {};                          // [qsub][dsub] O^T
    float mrun[2] = {-1e30f, -1e30f}, lrun[2] = {0.f, 0.f};

    const int kt0 = (q0 >= WIN_) ? ((q0 - (WIN_ - 1)) >> 6) : 0;
    const int kt1 = qt;

    const int srow = tid >> 3;
    const int schunk = (tid & 7) ^ (srow & 7);
    const u16* Ksrc = Kp + (size_t)srow * 64 + schunk * 8;   // + kt*4096 elems
    const u16* Vsrc = Vp + (size_t)srow * T_ + schunk * 8;   // + kt*64 elems
    const int ldsOff = wave * 512;               // u16; HW adds lane*16B

    // prologue: stage tile kt0 into buffer 0
    load_lds16(Ksrc + (size_t)kt0 * 4096, &Ks[0][ldsOff]);
    load_lds16(Vsrc + kt0 * 64, &Vs[0][ldsOff]);

    for (int kt = kt0; kt <= kt1; ++kt) {
        const int kbase = kt << 6;
        const int cur = (kt - kt0) & 1;
        if (kt < kt1) {
            load_lds16(Ksrc + (size_t)(kt + 1) * 4096, &Ks[cur ^ 1][ldsOff]);
            load_lds16(Vsrc + (kt + 1) * 64, &Vs[cur ^ 1][ldsOff]);
            WAITBAR(2);    // tile kt staged; kt+1's 2 loads stay in flight
        } else {
            WAITBAR(0);
        }
        bf16x8 kf[4][2], vb[4][2];
#pragma unroll
        for (int st = 0; st < 4; st++) {
            const int r64 = (st * 16 + m) * 64;
#pragma unroll
            for (int hf = 0; hf < 2; hf++) {
                const int c = (((hf << 2) + quad) ^ (m & 7)) * 8;
                kf[st][hf] = *(const bf16x8*)&Ks[cur][r64 + c];
                vb[st][hf] = *(const bf16x8*)&Vs[cur][r64 + c];
            }
        }
#pragma unroll
        for (int qs = 0; qs < 2; qs++) {
            const int qlo_s = qbase + qs * 16;
            if (kbase <= qlo_s + 15 && kbase >= qlo_s - 574) {   // any valid (q,k)
                f32x4 s4[4];
#pragma unroll
                for (int st = 0; st < 4; st++) {
                    f32x4 z = {0.f, 0.f, 0.f, 0.f};
                    z = __builtin_amdgcn_mfma_f32_16x16x32_bf16(kf[st][0], qa[qs][0], z, 0, 0, 0);
                    z = __builtin_amdgcn_mfma_f32_16x16x32_bf16(kf[st][1], qa[qs][1], z, 0, 0, 0);
                    s4[st] = z;
                }
                float v[16];
                const bool full = (kbase + 63 <= qlo_s) && (kbase >= qlo_s - 496);
                if (full) {
#pragma unroll
                    for (int i = 0; i < 16; i++) v[i] = s4[i >> 2][i & 3] * 0.125f;
                } else {
                    const int D = qlo_s + m - kbase - quad * 4;
#pragma unroll
                    for (int st = 0; st < 4; st++)
#pragma unroll
                        for (int r = 0; r < 4; r++) {
                            int diff = D - st * 16 - r;          // q - k
                            v[st * 4 + r] = ((u32)diff < (u32)WIN_) ? s4[st][r] * 0.125f : -INFINITY;
                        }
                }
                float t0 = fmaxf(fmaxf(fmaxf(v[0], v[1]), fmaxf(v[2], v[3])),
                                 fmaxf(fmaxf(v[4], v[5]), fmaxf(v[6], v[7])));
                float t1 = fmaxf(fmaxf(fmaxf(v[8], v[9]), fmaxf(v[10], v[11])),
                                 fmaxf(fmaxf(v[12], v[13]), fmaxf(v[14], v[15])));
                float rmax = fmaxf(t0, t1);
                rmax = fmaxf(rmax, __shfl_xor(rmax, 16));
                rmax = fmaxf(rmax, __shfl_xor(rmax, 32));
                float mnew = fmaxf(mrun[qs], rmax);
                float alpha = __expf(mrun[qs] - mnew);
                float p[16];
#pragma unroll
                for (int i = 0; i < 16; i++) p[i] = __expf(v[i] - mnew);
                float u0 = ((p[0] + p[1]) + (p[2] + p[3])) + ((p[4] + p[5]) + (p[6] + p[7]));
                float u1 = ((p[8] + p[9]) + (p[10] + p[11])) + ((p[12] + p[13]) + (p[14] + p[15]));
                float psum = u0 + u1;
                psum += __shfl_xor(psum, 16);
                psum += __shfl_xor(psum, 32);
                lrun[qs] = lrun[qs] * alpha + psum;
                mrun[qs] = mnew;
#pragma unroll
                for (int d = 0; d < 4; d++) {
                    o[qs][d][0] *= alpha; o[qs][d][1] *= alpha;
                    o[qs][d][2] *= alpha; o[qs][d][3] *= alpha;
                }
#pragma unroll
                for (int st = 0; st < 4; st++) {
                    u32 lo = (u32)f2bf(p[st * 4 + 0]) | ((u32)f2bf(p[st * 4 + 1]) << 16);
                    u32 hi = (u32)f2bf(p[st * 4 + 2]) | ((u32)f2bf(p[st * 4 + 3]) << 16);
                    *(uint2*)&Ps[wave][m * 72 + st * 16 + quad * 4] = make_uint2(lo, hi);
                }
                bf16x8 pa0 = *(const bf16x8*)&Ps[wave][m * 72 + quad * 8];
                bf16x8 pa1 = *(const bf16x8*)&Ps[wave][m * 72 + 32 + quad * 8];
#pragma unroll
                for (int d = 0; d < 4; d++) {
                    o[qs][d] = __builtin_amdgcn_mfma_f32_16x16x32_bf16(vb[d][0], pa0, o[qs][d], 0, 0, 0);
                    o[qs][d] = __builtin_amdgcn_mfma_f32_16x16x32_bf16(vb[d][1], pa1, o[qs][d], 0, 0, 0);
                }
            }
        }
        asm volatile("s_barrier" ::: "memory");  // all waves done reading buf cur
    }
    // epilogue: per qsub, O^T -> att8[qrow][h*64 + d], fp8 x8
#pragma unroll
    for (int qs = 0; qs < 2; qs++) {
        float inv = 8.0f / lrun[qs];             // x8 for fp8 encoding
        u8* ob = Ob8 + ((size_t)(b * T_ + qbase + qs * 16 + m)) * (H_ * HD_) + h * HD_;
#pragma unroll
        for (int d = 0; d < 4; d++) {
            int pk = __builtin_amdgcn_cvt_pk_fp8_f32(o[qs][d][0] * inv, o[qs][d][1] * inv, 0, false);
            pk = __builtin_amdgcn_cvt_pk_fp8_f32(o[qs][d][2] * inv, o[qs][d][3] * inv, pk, true);
            *(u32*)(ob + d * 16 + quad * 4) = (u32)pk;
        }
    }
}

#define MFMA8(a, b, c) __builtin_amdgcn_mfma_scale_f32_32x32x64_f8f6f4(a, b, c, 0, 0, 0, SCALE_A, 0, SCALE_B)
#define PHASE_MFMA(I0, I1)                           \
    __builtin_amdgcn_s_setprio(1);                   \
    acc[I0][0] = MFMA8(a0, bf0, acc[I0][0]);         \
    acc[I0][1] = MFMA8(a0, bf1, acc[I0][1]);         \
    acc[I1][0] = MFMA8(a1, bf0, acc[I1][0]);         \
    acc[I1][1] = MFMA8(a1, bf1, acc[I1][1]);         \
    __builtin_amdgcn_s_setprio(0);

// ---------------- fp8 MX GEMM (32x32x64), 256x256 tile, COALESCED staging (FROZEN r9) ----------------
// Used for the big w13 SwiGLU GEMM only (MODE 1).
template <int MODE>
__global__ __launch_bounds__(512) void gemm_fp8(const u8* __restrict__ A,
                                                const u8* __restrict__ Bt,
                                                u16* __restrict__ Cb,
                                                u8* __restrict__ C8,
                                                int M, int N, int K, int KS) {
    __shared__ __align__(16) u8 As[2][32768];
    __shared__ __align__(16) u8 Bs[2][32768];
    const int tid = threadIdx.x, wave = tid >> 6, lane = tid & 63;
    const int l31 = lane & 31, lh = lane >> 5;
    const int m0 = blockIdx.y * 256, n0 = blockIdx.x * 256;
    const int wm = (wave >> 2) * 128, wn = (wave & 3) * 64;
    const int kb = blockIdx.z * KS;
    const int KT = KS >> 7;

    const u8* Ab = A + (size_t)m0 * K;
    const u8* Bb = Bt + (size_t)n0 * K;

    auto STAGE = [&](const u8* src, int kk, int h, u8* lds) {
#pragma unroll
        for (int p = 0; p < 2; p++) {
            const int s = p * 512 + tid;
            const int r = (h << 7) + (s >> 3);
            const int c = (s & 7) ^ (r & 7);
            load_lds16(src + (size_t)r * K + kk + c * 16,
                       lds + (h << 14) + (p << 13) + (wave << 10));
        }
    };
    auto FRAG = [&](const u8* t, int ks, int row) -> i32x8 {
        const int c0 = ks * 4 + (lh << 1);
        const u8* rp = t + row * 128;
        union { i32x4 h[2]; i32x8 v; } u;
        u.h[0] = *(const i32x4*)(rp + ((c0 ^ (row & 7)) << 4));
        u.h[1] = *(const i32x4*)(rp + (((c0 + 1) ^ (row & 7)) << 4));
        return u.v;
    };

    f32x16 acc[4][2] = {};

    STAGE(Ab, kb, 0, As[0]);
    STAGE(Ab, kb, 1, As[0]);
    STAGE(Bb, kb, 0, Bs[0]);
    STAGE(Bb, kb, 1, Bs[0]);

    for (int kt = 0; kt < KT; ++kt) {
        const int cur = kt & 1;
        if (kt + 1 < KT) {
            asm volatile("s_barrier" ::: "memory");
            const int kn = kb + (kt + 1) * 128;
            STAGE(Ab, kn, 0, As[1 - cur]);
            STAGE(Ab, kn, 1, As[1 - cur]);
            STAGE(Bb, kn, 0, Bs[1 - cur]);
            STAGE(Bb, kn, 1, Bs[1 - cur]);
            WAITBAR(8);   // tile kt's 8 loads done; kt+1's 8 stay in flight
        } else {
            WAITBAR(0);
        }
        const u8* Ac = As[cur];
        const u8* Bc = Bs[cur];
        i32x8 bf0, bf1, a0, a1;
#pragma unroll
        for (int ks = 0; ks < 2; ks++) {
            bf0 = FRAG(Bc, ks, wn + l31);
            bf1 = FRAG(Bc, ks, wn + 32 + l31);
            a0 = FRAG(Ac, ks, wm + l31);
            a1 = FRAG(Ac, ks, wm + 32 + l31);
            PHASE_MFMA(0, 1)
            a0 = FRAG(Ac, ks, wm + 64 + l31);
            a1 = FRAG(Ac, ks, wm + 96 + l31);
            PHASE_MFMA(2, 3)
        }
    }

    if (MODE == 0) {
        u16* Cz = Cb + (size_t)blockIdx.z * M * N;
#pragma unroll
        for (int i = 0; i < 4; i++)
#pragma unroll
            for (int j = 0; j < 2; j++) {
                int col = n0 + wn + j * 32 + l31;
#pragma unroll
                for (int reg = 0; reg < 16; reg++) {
                    int row = m0 + wm + i * 32 + (reg & 3) + 8 * (reg >> 2) + 4 * lh;
                    Cz[(size_t)row * N + col] = f2bf(acc[i][j][reg]);
                }
            }
    } else {
        // SwiGLU: acc[i][0] = g1-tile, acc[i][1] = g3-tile for same 32 real cols
        int c = (n0 >> 1) + (wn >> 1) + l31;
#pragma unroll
        for (int i = 0; i < 4; i++)
#pragma unroll
            for (int reg = 0; reg < 16; reg++) {
                int row = m0 + wm + i * 32 + (reg & 3) + 8 * (reg >> 2) + 4 * lh;
                float g1 = acc[i][0][reg], g3 = acc[i][1][reg];
                float res = (g1 / (1.f + __expf(-g1))) * g3 * 8.0f;  // x8 for fp8 encoding
                int p = __builtin_amdgcn_cvt_pk_fp8_f32(res, res, 0, false);
                C8[(size_t)row * (N >> 1) + c] = (u8)(p & 0xFF);
            }
    }
}

// ---------------- fp8 MX GEMM, 128x128 tile, z=1 (no split-K) ----------------
// Same r9 structure (coalesced row staging, c^(r&7) both-sides swizzle, counted
// vmcnt) on a 128x128 tile: LDS 64 KB -> 2 blocks/CU capacity; deep KT amortizes.
// Eliminates split-K partials: QKV/WO/w2 write ONE bf16 result (saves ~90 MB of
// partial round-trip across the pipeline). 512 thr = 8 waves (2M x 4N), per-wave
// 64x32 output = acc[2] of 32x32.
__global__ __launch_bounds__(512) void gemm_fp8_s(const u8* __restrict__ A,
                                                  const u8* __restrict__ Bt,
                                                  u16* __restrict__ Cb,
                                                  int M, int N, int K) {
    __shared__ __align__(16) u8 As[2][16384];
    __shared__ __align__(16) u8 Bs[2][16384];
    const int tid = threadIdx.x, wave = tid >> 6, lane = tid & 63;
    const int l31 = lane & 31, lh = lane >> 5;
    const int m0 = blockIdx.y * 128, n0 = blockIdx.x * 128;
    const int wm = (wave >> 2) * 64, wn = (wave & 3) * 32;
    const int KT = K >> 7;

    const u8* Ab = A + (size_t)m0 * K;
    const u8* Bb = Bt + (size_t)n0 * K;

    // stage one matrix K-tile (128 rows x 128B = 16 KB): 2 loads/thread.
    // slot s = p*512+tid -> row r = s>>3, chunk c = (s&7)^(r&7) (8 lanes = one row,
    // coalesced). LDS dest linear: p*8192 + wave*1024 (+ lane*16 by HW).
    auto STAGE = [&](const u8* src, int kk, u8* lds) {
#pragma unroll
        for (int p = 0; p < 2; p++) {
            const int s = p * 512 + tid;
            const int r = s >> 3;
            const int c = (s & 7) ^ (r & 7);
            load_lds16(src + (size_t)r * K + kk + c * 16,
                       lds + (p << 13) + (wave << 10));
        }
    };
    auto FRAG = [&](const u8* t, int ks, int row) -> i32x8 {
        const int c0 = ks * 4 + (lh << 1);
        const u8* rp = t + row * 128;
        union { i32x4 h[2]; i32x8 v; } u;
        u.h[0] = *(const i32x4*)(rp + ((c0 ^ (row & 7)) << 4));
        u.h[1] = *(const i32x4*)(rp + (((c0 + 1) ^ (row & 7)) << 4));
        return u.v;
    };

    f32x16 acc[2] = {};

    STAGE(Ab, 0, As[0]);
    STAGE(Bb, 0, Bs[0]);

    for (int kt = 0; kt < KT; ++kt) {
        const int cur = kt & 1;
        if (kt + 1 < KT) {
            asm volatile("s_barrier" ::: "memory");
            const int kn = (kt + 1) * 128;
            STAGE(Ab, kn, As[1 - cur]);
            STAGE(Bb, kn, Bs[1 - cur]);
            WAITBAR(4);   // tile kt's 4 loads done; kt+1's 4 stay in flight
        } else {
            WAITBAR(0);
        }
        const u8* Ac = As[cur];
        const u8* Bc = Bs[cur];
#pragma unroll
        for (int ks = 0; ks < 2; ks++) {
            i32x8 bf0 = FRAG(Bc, ks, wn + l31);
            i32x8 a0 = FRAG(Ac, ks, wm + l31);
            i32x8 a1 = FRAG(Ac, ks, wm + 32 + l31);
            __builtin_amdgcn_s_setprio(1);
            acc[0] = MFMA8(a0, bf0, acc[0]);
            acc[1] = MFMA8(a1, bf0, acc[1]);
            __builtin_amdgcn_s_setprio(0);
        }
    }

    int col = n0 + wn + l31;
#pragma unroll
    for (int i = 0; i < 2; i++)
#pragma unroll
        for (int reg = 0; reg < 16; reg++) {
            int row = m0 + wm + i * 32 + (reg & 3) + 8 * (reg >> 2) + 4 * lh;
            Cb[(size_t)row * N + col] = f2bf(acc[i][reg]);
        }
}

extern "C" void kernel_launch(void* const* d_in, const int* in_sizes, int n_in,
                              void* d_out, int out_size, void* d_ws, size_t ws_size,
                              hipStream_t stream) {
    const float* x = (const float*)d_in[0];
    const float* wq = (const float*)d_in[1];
    const float* wk = (const float*)d_in[2];
    const float* wv = (const float*)d_in[3];
    const float* wo = (const float*)d_in[4];
    const float* w1 = (const float*)d_in[5];
    const float* w2 = (const float*)d_in[6];
    const float* w3 = (const float*)d_in[7];
    const float* qnw = (const float*)d_in[8];
    const float* knw = (const float*)d_in[9];
    const float* anw = (const float*)d_in[10];
    const float* fnw = (const float*)d_in[11];
    const float* ascale = (const float*)d_in[12];
    const float* fscale = (const float*)d_in[13];
    float* out = (float*)d_out;

    // ---- workspace layout ----
    char* ws = (char*)d_ws;
    u8* wqkv8 = (u8*)(ws + 0);              // [1536][1024] fp8 (x64)
    u8* wo8 = (u8*)(ws + 1572864);          // [1024][1024] fp8 (x64)
    u8* w13_8 = (u8*)(ws + 5242880);        // [8192][1024] fp8 (x64, 32-col interleave)
    u8* w2_8 = (u8*)(ws + 13631488);        // [1024][4096] fp8 (x64)
    u8* xq8 = (u8*)(ws + 17825792);         // [4096][1024] fp8 (x8, attn-norm out)
    u8* xn8 = (u8*)(ws + 26214400);         // [4096][1024] fp8 (x8, ffn-norm out)
    float* h_f = (float*)(ws + 30408704);   // [4096][1024] fp32
    char* P = ws + 47185920;                // overlay pool (67.1 MB)
    u16* qkv_part = (u16*)(P + 0);          // [4096][1536] bf16 (single, z=1)
    u16* Qb = (u16*)(P + 25165824);
    u16* Kb = (u16*)(P + 33554432);
    u8* att8 = (u8*)(P + 37748736);         // [4096][1024] fp8 (x8, flash out)
    u16* Vt = (u16*)(P + 46137344);         // [8][64][2048] bf16 (V^T, by qkv_post)
    u16* wo_part = (u16*)(P + 0);           // [4096][1024] bf16 (single, z=1)
    u8* gsw8 = (u8*)(P + 16777216);         // [4096][4096] fp8
    u16* w2_part = (u16*)(P + 33554432);    // [4096][1024] bf16 (single, z=1)

    // weights -> fp8 + attn rmsnorm, one launch
    mega_cvt<<<18944, 256, 0, stream>>>(wq, wk, wv, wo, w1, w3, w2,
                                        wqkv8, wo8, w13_8, w2_8, x, anw, xq8);
    // QKV projection: 128x128 tiles, z=1 -> single bf16 result (384 blocks, KT=8)
    gemm_fp8_s<<<dim3(12, 32, 1), 512, 0, stream>>>(xq8, wqkv8, qkv_part,
                                                    4096, 1536, 1024);
    // per-head norms; writes Q, K and V^T directly
    qkv_post_kernel<<<4096, 256, 0, stream>>>(qkv_part, qnw, knw, Qb, Kb, Vt);
    // GQA-shared flash: grid (qt, kvh, b) = 256 blocks, 8 waves = 4 heads x 2 q-halves
    flash_kernel<<<dim3(32, KVH_, B_), 512, 0, stream>>>(Qb, Kb, Vt, att8);
    // out-proj: 128x128 tiles, z=1 (256 blocks, KT=8)
    gemm_fp8_s<<<dim3(8, 32, 1), 512, 0, stream>>>(att8, wo8, wo_part,
                                                   4096, 1024, 1024);
    fuse_attn_kernel<<<4096, 256, 0, stream>>>(x, wo_part, ascale, fnw, h_f, xn8);
    // w1|w3 fp8-MX GEMM with fused SwiGLU -> gsw8 (512 blocks, frozen 256^2 kernel)
    gemm_fp8<1><<<dim3(32, 16, 1), 512, 0, stream>>>(xn8, w13_8, nullptr, gsw8,
                                                     4096, 8192, 1024, 1024);
    // w2: 128x128 tiles, z=1 (256 blocks, KT=32)
    gemm_fp8_s<<<dim3(8, 32, 1), 512, 0, stream>>>(gsw8, w2_8, w2_part,
                                                   4096, 1024, 4096);
    fuse_ffn_kernel<<<4096, 256, 0, stream>>>(h_f, w2_part, fscale, out);
}